// Round 3
// baseline (485.045 us; speedup 1.0000x reference)
//
#include <hip/hip_runtime.h>

// RWKV WKV forward scan — R3: LDS double-buffer with EXPLICIT vmcnt drains.
//
// R2 post-mortem: first-call correct, graph-replay validation failed ->
// race. global_load_lds completion is tracked by vmcnt, but for a
// single-wave workgroup the compiler elides s_barrier and fails to insert
// the vmcnt wait before the dependent ds_read. Fix: explicit
// `s_waitcnt vmcnt(N)` via asm volatile with memory clobbers, plus a
// compiler fence after the prefetch block so issue order is pinned:
// [32 loads chunk c+1] then [16 stores chunk c]. Steady-state wait is
// vmcnt(16): drains exactly the 32 oldest (chunk-c loads) without waiting
// on the previous chunk's store acks. First iteration peels with vmcnt(0).

#ifndef TCH
#define TCH 16   // steps per chunk; S=2048 divisible
#endif

#define VM_WAIT0  asm volatile("s_waitcnt vmcnt(0)" ::: "memory")
#define VM_WAIT16 asm volatile("s_waitcnt vmcnt(16)" ::: "memory")
#define CFENCE    asm volatile("" ::: "memory")

__device__ __forceinline__ float ex2(float x)  { return __builtin_amdgcn_exp2f(x); }
__device__ __forceinline__ float rcpf(float x) { return __builtin_amdgcn_rcpf(x); }

__device__ __forceinline__ void gload_lds4(const float* g, float* l) {
    __builtin_amdgcn_global_load_lds(
        (const __attribute__((address_space(1))) unsigned int*)g,
        (__attribute__((address_space(3))) unsigned int*)l,
        4, 0, 0);
}

// kts = k_t*log2e ; tfs = time_first*log2e ; tds = -exp(time_decay)*log2e
// m carried scaled by log2e; num/den unscaled. All exp2 args <= 0.
__device__ __forceinline__ float wkv_step(float kts, float vt, float tfs, float tds,
                                          float& m, float& num, float& den)
{
    const float ktf = kts + tfs;
    const float mo  = fmaxf(m, ktf);
    const float e1o = ex2(m - mo);
    const float e2o = ex2(ktf - mo);
    const float o   = (e1o * num + e2o * vt) * rcpf(e1o * den + e2o);
    const float mpd = m + tds;
    const float ms  = fmaxf(mpd, kts);
    const float e1s = ex2(mpd - ms);
    const float e2s = ex2(kts - ms);
    num = e1s * num + e2s * vt;
    den = e1s * den + e2s;
    m   = ms;
    return o;
}

__global__ __launch_bounds__(64, 1)
void wkv_fwd(const float* __restrict__ td_in, const float* __restrict__ kin,
             const float* __restrict__ tf_in, const float* __restrict__ vin,
             const float* __restrict__ m0, const float* __restrict__ n0,
             const float* __restrict__ d0,
             float* __restrict__ out, float* __restrict__ m_out,
             float* __restrict__ n_out, float* __restrict__ dn_out,
             int B, int S, int H)
{
    // [buf][step][k/v][lane] — 2*TCH*2*64*4 B = 16 KiB
    __shared__ float lds[2][TCH][2][64];

    const int lane = threadIdx.x;
    int g = blockIdx.x * 64 + lane;
    if (g >= B * H) g = B * H - 1;   // same-value dup writes; keeps wave convergent
    const int b = g / H;
    const int h = g - b * H;

    constexpr float C  = 1.4426950408889634f;   // log2(e)
    constexpr float IC = 0.6931471805599453f;   // ln(2)

    const float tds = -ex2(td_in[h] * C) * C;
    const float tfs = tf_in[h] * C;

    float m   = m0[g] * C;
    float num = n0[g];
    float den = d0[g];

    const size_t base = (size_t)b * (size_t)S * (size_t)H + (size_t)h;
    const float* kp = kin + base;
    const float* vp = vin + base;
    float*       op = out + base;

    const int nc = S / TCH;
    int t = 0;

    if (nc > 0) {
        // Prologue: prefetch chunk 0 into buf 0.
        CFENCE;
        #pragma unroll
        for (int i = 0; i < TCH; ++i) {
            gload_lds4(kp + (size_t)i * H, &lds[0][i][0][0]);
            gload_lds4(vp + (size_t)i * H, &lds[0][i][1][0]);
        }
        CFENCE;

        for (int c = 0; c < nc; ++c) {
            const int bf = c & 1;
            // Drain chunk c's 32 loads. c==0: nothing else outstanding ->
            // vmcnt(0). c>0: 16 stores (chunk c-1) are newer -> vmcnt(16)
            // drains exactly the 32 oldest (the loads), skips store acks.
            if (c == 0) { VM_WAIT0; } else { VM_WAIT16; }

            if (c + 1 < nc) {
                const int nb = bf ^ 1;
                const size_t t1 = (size_t)t + TCH;
                #pragma unroll
                for (int i = 0; i < TCH; ++i) {
                    gload_lds4(kp + (t1 + i) * (size_t)H, &lds[nb][i][0][0]);
                    gload_lds4(vp + (t1 + i) * (size_t)H, &lds[nb][i][1][0]);
                }
            }
            CFENCE;  // pin order: prefetch loads precede compute stores

            #pragma unroll
            for (int i = 0; i < TCH; ++i) {
                const float kt = lds[bf][i][0][lane];
                const float vt = lds[bf][i][1][lane];
                op[(size_t)(t + i) * H] = wkv_step(kt * C, vt, tfs, tds, m, num, den);
            }
            CFENCE;
            t += TCH;
        }
    }

    for (; t < S; ++t) {   // generic tail (unused for S=2048)
        const float kt = kp[(size_t)t * H];
        const float vt = vp[(size_t)t * H];
        op[(size_t)t * H] = wkv_step(kt * C, vt, tfs, tds, m, num, den);
    }

    m_out[g]  = m * IC;
    n_out[g]  = num;
    dn_out[g] = den;
}

extern "C" void kernel_launch(void* const* d_in, const int* in_sizes, int n_in,
                              void* d_out, int out_size, void* d_ws, size_t ws_size,
                              hipStream_t stream)
{
    const float* time_decay = (const float*)d_in[0];
    const float* key        = (const float*)d_in[1];
    const float* time_first = (const float*)d_in[2];
    const float* value      = (const float*)d_in[3];
    const float* max_state  = (const float*)d_in[4];
    const float* num_state  = (const float*)d_in[5];
    const float* den_state  = (const float*)d_in[6];

    const int H  = in_sizes[0];
    const int BH = in_sizes[4];
    const int B  = BH / H;
    const int S  = in_sizes[1] / BH;

    float* out    = (float*)d_out;
    float* m_out  = out + (size_t)B * (size_t)S * (size_t)H;
    float* n_out  = m_out + BH;
    float* dn_out = n_out + BH;

    const int grid = (BH + 63) / 64;
    wkv_fwd<<<grid, 64, 0, stream>>>(time_decay, key, time_first, value,
                                     max_state, num_state, den_state,
                                     out, m_out, n_out, dn_out, B, S, H);
}

// Round 4
// 349.310 us; speedup vs baseline: 1.3886x; 1.3886x over previous
//
#include <hip/hip_runtime.h>

// RWKV WKV forward — R4: blocked (segmented) scan, 8 waves/CU.
//
// Identity: with P=(num,den) scaled by 2^m, the step is the linear recurrence
// P' = 2^{tds} P + 2^{kts} (v,1), decay channel-constant => associative,
// segment compose = "decay by L, add local sum".
// Block = 512 thr (8 waves) owns 64 contiguous channels; sequence processed
// in tiles of 128 steps (LDS double-buffered, global_load_lds width=16).
// Per tile: each wave w scans steps [w*16,(w+1)*16): phase A local sums
// (init m=-1e30,n=d=0), barrier, prefix-compose (w iterations), phase B
// replay from true incoming state + coalesced output stores. Wave 7's end
// state is the tile carry (double-buffered in LDS).
// Waves only touch their OWN k/v LDS rows, so barriers protect only
// summaries/carry; per-wave vmcnt drains cover the DMA.

#define TILE 128
#define NW   8
#define SUB  (TILE / NW)   // 16

#define VMW0   asm volatile("s_waitcnt vmcnt(0)" ::: "memory")
#define VMW16  asm volatile("s_waitcnt vmcnt(16)" ::: "memory")
#define BARR   asm volatile("s_waitcnt lgkmcnt(0)\n\ts_barrier" ::: "memory")

__device__ __forceinline__ float ex2(float x)  { return __builtin_amdgcn_exp2f(x); }
__device__ __forceinline__ float rcpf(float x) { return __builtin_amdgcn_rcpf(x); }

__device__ __forceinline__ void dma16(const float* g, float* l) {
    __builtin_amdgcn_global_load_lds(
        (const __attribute__((address_space(1))) unsigned int*)g,
        (__attribute__((address_space(3))) unsigned int*)l, 16, 0, 0);
}

__global__ __launch_bounds__(512)
void wkv_fwd(const float* __restrict__ td_in, const float* __restrict__ kin,
             const float* __restrict__ tf_in, const float* __restrict__ vin,
             const float* __restrict__ m0, const float* __restrict__ n0,
             const float* __restrict__ d0,
             float* __restrict__ out, float* __restrict__ m_out,
             float* __restrict__ n_out, float* __restrict__ dn_out,
             int B, int S, int H)
{
    __shared__ float kbuf[2][TILE][64];      // 64 KiB
    __shared__ float vbuf[2][TILE][64];      // 64 KiB
    __shared__ float smry[NW][3][64];        // 6 KiB
    __shared__ float cry[2][3][64];          // 1.5 KiB

    const int tid  = threadIdx.x;
    const int lane = tid & 63;
    const int w    = tid >> 6;               // wave id 0..7

    const int bpb = H >> 6;                  // blocks per batch
    const int b   = blockIdx.x / bpb;
    const int hb  = (blockIdx.x - b * bpb) << 6;
    const int h   = hb + lane;
    const int g   = b * H + h;

    constexpr float Cc = 1.4426950408889634f;   // log2(e)
    constexpr float IC = 0.6931471805599453f;   // ln(2)

    const float tds  = -ex2(td_in[h] * Cc) * Cc;  // per-step decay, log2 units
    const float tfs  = tf_in[h] * Cc;
    const float dseg = tds * (float)SUB;          // decay over one sub-segment

    if (w == 0) {                                 // tile-0 carry = init state
        cry[0][0][lane] = m0[g] * Cc;
        cry[0][1][lane] = n0[g];
        cry[0][2][lane] = d0[g];
    }

    const size_t base = (size_t)b * (size_t)S * (size_t)H + (size_t)hb;
    const float* gk = kin + base;
    const float* gv = vin + base;
    float*       go = out + base;

    const int sub = lane >> 4;                    // 0..3 (row within 4-row DMA)
    const int c4  = (lane & 15) << 2;             // channel offset (4 floats/lane)

    const int ntiles = S / TILE;

    // Prologue: DMA tile 0 into buffer 0 (each wave its own 16 rows of k and v).
    #pragma unroll
    for (int i = 0; i < 4; ++i) {
        const int r = w * SUB + i * 4;
        dma16(gk + (size_t)(r + sub) * H + c4, &kbuf[0][r][0]);
        dma16(gv + (size_t)(r + sub) * H + c4, &vbuf[0][r][0]);
    }

    float M = 0.f, N = 0.f, D = 0.f;

    for (int it = 0; it < ntiles; ++it) {
        const int p = it & 1;
        // Drain this tile's 8 DMA ops (per-wave). Steady state: 16 newer
        // output stores may remain outstanding -> vmcnt(16).
        if (it == 0) { VMW0; } else { VMW16; }
        BARR;                                   // publish smry/cry ordering

        if (it + 1 < ntiles) {                  // prefetch next tile
            const int np = p ^ 1;
            const size_t t1 = (size_t)(it + 1) * TILE;
            #pragma unroll
            for (int i = 0; i < 4; ++i) {
                const int r = w * SUB + i * 4;
                dma16(gk + (t1 + r + sub) * (size_t)H + c4, &kbuf[np][r][0]);
                dma16(gv + (t1 + r + sub) * (size_t)H + c4, &vbuf[np][r][0]);
            }
        }

        // ---- Phase A: local scan (state branch only), neutral init ----
        float lm = -1e30f, ln = 0.f, ldn = 0.f;
        #pragma unroll
        for (int j = 0; j < SUB; ++j) {
            const float kt  = kbuf[p][w * SUB + j][lane] * Cc;
            const float vt  = vbuf[p][w * SUB + j][lane];
            const float mpd = lm + tds;
            const float ms  = fmaxf(mpd, kt);
            const float e1  = ex2(mpd - ms);
            const float e2  = ex2(kt - ms);
            ln  = e1 * ln  + e2 * vt;
            ldn = e1 * ldn + e2;
            lm  = ms;
        }
        smry[w][0][lane] = lm;
        smry[w][1][lane] = ln;
        smry[w][2][lane] = ldn;
        BARR;

        // ---- Prefix compose: incoming state for this wave ----
        M = cry[p][0][lane];
        N = cry[p][1][lane];
        D = cry[p][2][lane];
        for (int j = 0; j < w; ++j) {
            const float Md = M + dseg;
            const float sm = smry[j][0][lane];
            const float M2 = fmaxf(Md, sm);
            const float a  = ex2(Md - M2);
            const float bb = ex2(sm - M2);
            N = a * N + bb * smry[j][1][lane];
            D = a * D + bb * smry[j][2][lane];
            M = M2;
        }

        // ---- Phase B: replay with outputs (coalesced 256 B row stores) ----
        float* po = go + ((size_t)it * TILE + (size_t)w * SUB) * (size_t)H;
        #pragma unroll
        for (int j = 0; j < SUB; ++j) {
            const float kt  = kbuf[p][w * SUB + j][lane] * Cc;
            const float vt  = vbuf[p][w * SUB + j][lane];
            const float ktf = kt + tfs;
            const float mo  = fmaxf(M, ktf);
            const float e1o = ex2(M - mo);
            const float e2o = ex2(ktf - mo);
            po[(size_t)j * H + lane] =
                (e1o * N + e2o * vt) * rcpf(e1o * D + e2o);
            const float mpd = M + tds;
            const float ms  = fmaxf(mpd, kt);
            const float e1s = ex2(mpd - ms);
            const float e2s = ex2(kt - ms);
            N = e1s * N + e2s * vt;
            D = e1s * D + e2s;
            M = ms;
        }

        if (w == NW - 1) {                      // tile carry (double-buffered)
            cry[p ^ 1][0][lane] = M;
            cry[p ^ 1][1][lane] = N;
            cry[p ^ 1][2][lane] = D;
        }
    }

    if (w == NW - 1) {                          // final states
        m_out[g]  = M * IC;
        n_out[g]  = N;
        dn_out[g] = D;
    }
}

// Safety fallback (serial per channel) for shapes the tiled kernel can't take.
__global__ __launch_bounds__(64)
void wkv_fwd_serial(const float* __restrict__ td_in, const float* __restrict__ kin,
                    const float* __restrict__ tf_in, const float* __restrict__ vin,
                    const float* __restrict__ m0, const float* __restrict__ n0,
                    const float* __restrict__ d0,
                    float* __restrict__ out, float* __restrict__ m_out,
                    float* __restrict__ n_out, float* __restrict__ dn_out,
                    int B, int S, int H)
{
    const int g = blockIdx.x * 64 + threadIdx.x;
    if (g >= B * H) return;
    const int b = g / H;
    const int h = g - b * H;
    constexpr float Cc = 1.4426950408889634f, IC = 0.6931471805599453f;
    const float tds = -ex2(td_in[h] * Cc) * Cc;
    const float tfs = tf_in[h] * Cc;
    float M = m0[g] * Cc, N = n0[g], D = d0[g];
    const size_t base = (size_t)b * S * H + h;
    for (int t = 0; t < S; ++t) {
        const float kt  = kin[base + (size_t)t * H] * Cc;
        const float vt  = vin[base + (size_t)t * H];
        const float ktf = kt + tfs;
        const float mo  = fmaxf(M, ktf);
        const float e1o = ex2(M - mo), e2o = ex2(ktf - mo);
        out[base + (size_t)t * H] = (e1o * N + e2o * vt) * rcpf(e1o * D + e2o);
        const float mpd = M + tds;
        const float ms  = fmaxf(mpd, kt);
        const float e1s = ex2(mpd - ms), e2s = ex2(kt - ms);
        N = e1s * N + e2s * vt;
        D = e1s * D + e2s;
        M = ms;
    }
    m_out[g] = M * IC; n_out[g] = N; dn_out[g] = D;
}

extern "C" void kernel_launch(void* const* d_in, const int* in_sizes, int n_in,
                              void* d_out, int out_size, void* d_ws, size_t ws_size,
                              hipStream_t stream)
{
    const float* time_decay = (const float*)d_in[0];
    const float* key        = (const float*)d_in[1];
    const float* time_first = (const float*)d_in[2];
    const float* value      = (const float*)d_in[3];
    const float* max_state  = (const float*)d_in[4];
    const float* num_state  = (const float*)d_in[5];
    const float* den_state  = (const float*)d_in[6];

    const int H  = in_sizes[0];
    const int BH = in_sizes[4];
    const int B  = BH / H;
    const int S  = in_sizes[1] / BH;

    float* out    = (float*)d_out;
    float* m_out  = out + (size_t)B * (size_t)S * (size_t)H;
    float* n_out  = m_out + BH;
    float* dn_out = n_out + BH;

    if ((H % 64 == 0) && (S % TILE == 0)) {
        const int grid = BH / 64;               // 256 blocks, 1/CU
        wkv_fwd<<<grid, 512, 0, stream>>>(time_decay, key, time_first, value,
                                          max_state, num_state, den_state,
                                          out, m_out, n_out, dn_out, B, S, H);
    } else {
        const int grid = (BH + 63) / 64;
        wkv_fwd_serial<<<grid, 64, 0, stream>>>(time_decay, key, time_first, value,
                                                max_state, num_state, den_state,
                                                out, m_out, n_out, dn_out, B, S, H);
    }
}